// Round 10
// baseline (187.491 us; speedup 1.0000x reference)
//
#include <hip/hip_runtime.h>

#define N_NODES 100000
#define N_EDGES 600000
#define DIM 128

typedef __attribute__((ext_vector_type(8))) short bf16x8;
typedef __attribute__((ext_vector_type(4))) float f32x4;

typedef __attribute__((address_space(1))) const unsigned int g_u32;
typedef __attribute__((address_space(3))) unsigned int l_u32;
__device__ __forceinline__ void stage16(const void* g, void* l) {
  __builtin_amdgcn_global_load_lds((g_u32*)g, (l_u32*)l, 16, 0, 0);
}

__device__ __forceinline__ unsigned short f32_to_bf16_rn(float f) {
  unsigned int u = __builtin_bit_cast(unsigned int, f);
  unsigned int r = (u + 0x7FFFu + ((u >> 16) & 1u)) >> 16;
  return (unsigned short)r;
}

// ---------------- prep: pack weights (hi) + x -> bf16 hi plane ----------
// gid < 65536: weight packing (two layers x 32768).
// gid >= 65536: xsplit over 3.2M float4 -> bf16x4.
__global__ __launch_bounds__(256) void prep_k(
    const float* __restrict__ Wl0, const float* __restrict__ Wr0,
    const float* __restrict__ Wl1, const float* __restrict__ Wr1,
    unsigned short* __restrict__ P0, unsigned short* __restrict__ P1,
    const float* __restrict__ x, unsigned short* __restrict__ xhi) {
  const int gid = blockIdx.x * 256 + threadIdx.x;
  if (gid < 65536) {
    const int layer = gid >> 15;
    const int idx = gid & 32767;
    const int j = idx & 7;
    const int l = (idx >> 3) & 63;
    const int nt = (idx >> 9) & 7;
    const int g = idx >> 12;  // 0..7
    const int k = ((g & 3) << 5) + ((l >> 4) << 3) + j;
    const int n = (nt << 4) + (l & 15);
    const float* W = layer ? ((g < 4) ? Wl1 : Wr1) : ((g < 4) ? Wl0 : Wr0);
    (layer ? P1 : P0)[idx] = f32_to_bf16_rn(W[k * 128 + n]);
  } else {
    const int i = gid - 65536;  // one float4 per thread
    if (i < N_NODES * DIM / 4) {
      const float4 v = reinterpret_cast<const float4*>(x)[i];
      const float f[4] = {v.x, v.y, v.z, v.w};
      unsigned short h[4];
#pragma unroll
      for (int j = 0; j < 4; ++j) h[j] = f32_to_bf16_rn(f[j]);
      uint2 hp;
      hp.x = (unsigned)h[0] | ((unsigned)h[1] << 16);
      hp.y = (unsigned)h[2] | ((unsigned)h[3] << 16);
      reinterpret_cast<uint2*>(xhi)[i] = hp;
    }
  }
}

// ---------------- CSR build ----------------
__global__ void hist_k(const int* __restrict__ dst, int* __restrict__ deg) {
  int e = blockIdx.x * blockDim.x + threadIdx.x;
  if (e < N_EDGES) atomicAdd(&deg[dst[e]], 1);
}

__global__ __launch_bounds__(1024) void scan1_k(const int* __restrict__ deg,
                                                int* __restrict__ incl,
                                                int* __restrict__ bsum) {
  __shared__ int wsum[16];
  const int t = threadIdx.x, lane = t & 63, w = t >> 6;
  const int gi = blockIdx.x * 1024 + t;
  int v = (gi < N_NODES) ? deg[gi] : 0;
  int s = v;
#pragma unroll
  for (int off = 1; off < 64; off <<= 1) {
    int u = __shfl_up(s, off);
    if (lane >= off) s += u;
  }
  if (lane == 63) wsum[w] = s;
  __syncthreads();
  if (t < 16) {
    int ws = wsum[t];
#pragma unroll
    for (int off = 1; off < 16; off <<= 1) {
      int u = __shfl_up(ws, off);
      if (t >= off) ws += u;
    }
    wsum[t] = ws;
  }
  __syncthreads();
  const int val = s + (w ? wsum[w - 1] : 0);
  if (gi < N_NODES) incl[gi] = val;
  if (t == 1023) bsum[blockIdx.x] = val;
}

__global__ void scan2_k(const int* __restrict__ bsum, int* __restrict__ boffs,
                        int nb) {
  __shared__ int w0;
  const int t = threadIdx.x;  // 128 threads
  int v = (t < nb) ? bsum[t] : 0;
  int s = v;
#pragma unroll
  for (int off = 1; off < 64; off <<= 1) {
    int u = __shfl_up(s, off);
    if ((t & 63) >= off) s += u;
  }
  if (t == 63) w0 = s;
  __syncthreads();
  const int excl = s - v + ((t >> 6) ? w0 : 0);
  if (t < nb) boffs[t] = excl;
}

__global__ __launch_bounds__(1024) void scan3_k(const int* __restrict__ deg,
                                                const int* __restrict__ incl,
                                                const int* __restrict__ boffs,
                                                int* __restrict__ rowptr,
                                                int* __restrict__ head) {
  const int gi = blockIdx.x * 1024 + threadIdx.x;
  if (gi < N_NODES) {
    const int e = incl[gi] - deg[gi] + boffs[blockIdx.x];
    rowptr[gi] = e;
    head[gi] = e;
  }
  if (gi == 0) rowptr[N_NODES] = N_EDGES;
}

__global__ void fill_k(const int* __restrict__ src, const int* __restrict__ dst,
                       int* __restrict__ head, int* __restrict__ col) {
  int e = blockIdx.x * blockDim.x + threadIdx.x;
  if (e < N_EDGES) {
    int p = atomicAdd(&head[dst[e]], 1);
    col[p] = src[e];
  }
}

// ---------------- mean aggregation: gather bf16 hi-plane ----------------
// 16 nodes / 256-thread block; 16 lanes per node, 16 B (8 bf16) per lane.
// Depth-4 neighbor pipeline. Output: mean as bf16 hi plane.
__global__ __launch_bounds__(256) void agg_k(
    const unsigned short* __restrict__ plane, const int* __restrict__ rowptr,
    const int* __restrict__ col, unsigned short* __restrict__ mhi) {
  const int t = threadIdx.x;
  const int node = blockIdx.x * 16 + (t >> 4);
  const int q = t & 15;  // 16B granule within the 256B row
  const int beg = rowptr[node], end = rowptr[node + 1];
  const uint4* P = reinterpret_cast<const uint4*>(plane);
  float a[8] = {};

  auto accum = [&](uint4 v) {
    const unsigned int u[4] = {v.x, v.y, v.z, v.w};
#pragma unroll
    for (int w = 0; w < 4; ++w) {
      a[2 * w] += __builtin_bit_cast(float, u[w] << 16);
      a[2 * w + 1] += __builtin_bit_cast(float, u[w] & 0xFFFF0000u);
    }
  };

  for (int i = beg; i < end; i += 4) {
    const int i1 = min(i + 1, end - 1);
    const int i2 = min(i + 2, end - 1);
    const int i3 = min(i + 3, end - 1);
    const int c0 = col[i], c1 = col[i1], c2 = col[i2], c3 = col[i3];
    const uint4 v0 = P[(size_t)c0 * 16 + q];
    const uint4 v1 = P[(size_t)c1 * 16 + q];
    const uint4 v2 = P[(size_t)c2 * 16 + q];
    const uint4 v3 = P[(size_t)c3 * 16 + q];
    accum(v0);
    if (i + 1 < end) accum(v1);
    if (i + 2 < end) accum(v2);
    if (i + 3 < end) accum(v3);
  }

  const int d = end - beg;
  const float inv = 1.0f / (float)(d > 1 ? d : 1);
  unsigned int hw[4];
#pragma unroll
  for (int w = 0; w < 4; ++w) {
    const unsigned short h0 = f32_to_bf16_rn(a[2 * w] * inv);
    const unsigned short h1 = f32_to_bf16_rn(a[2 * w + 1] * inv);
    hw[w] = (unsigned)h0 | ((unsigned)h1 << 16);
  }
  uint4 ho = {hw[0], hw[1], hw[2], hw[3]};
  reinterpret_cast<uint4*>(mhi)[(size_t)node * 16 + q] = ho;
}

// ---------------- MFMA GEMM: out = relu(mean@Wl + b + h@Wr) ----------------
// Grid: 782 blocks x 128 rows. Block: 256 thr / 4 waves; wave = 32 rows
// (2 m-tiles) x N=128 (8 n-tiles). K loop: 8 g-tiles (g 0-3: Mhi x Wl;
// g 4-7: Hhi x Wr). B: 8 KB/g-tile, double-buffered LDS via global_load_lds,
// one barrier per g-tile; each staged B fragment feeds 2 MFMAs.
template <int OUTF32>
__global__ __launch_bounds__(256, 4) void gemm_k(
    const unsigned short* __restrict__ Mhi, const unsigned short* __restrict__ Hhi,
    const unsigned short* __restrict__ Bp, const float* __restrict__ bias,
    unsigned short* __restrict__ Ohi, float* __restrict__ Of) {
  __shared__ unsigned short Bl[2][4096];  // 8 KB per buffer
  const int t = threadIdx.x;
  const int lane = t & 63;
  const int wid = t >> 6;
  const int rbase = blockIdx.x * 128 + wid * 32;
  const int lm = lane & 15, lk = lane >> 4;
  const size_t r0 = (size_t)min(rbase + lm, N_NODES - 1);
  const size_t r1 = (size_t)min(rbase + 16 + lm, N_NODES - 1);

  f32x4 acc[2][8] = {};

  auto stageG = [&](int g, int nb) {
#pragma unroll
    for (int c = 0; c < 2; ++c) {
      const int e = (c * 256 + t) * 8;  // short index
      stage16(Bp + (size_t)g * 4096 + e, &Bl[nb][e]);
    }
  };
  auto loadA = [&](int g, bf16x8& a0, bf16x8& a1) {
    const unsigned short* P = (g < 4) ? Mhi : Hhi;
    const int ke = ((g & 3) << 5) + (lk << 3);
    a0 = *reinterpret_cast<const bf16x8*>(P + r0 * DIM + ke);
    a1 = *reinterpret_cast<const bf16x8*>(P + r1 * DIM + ke);
  };

  bf16x8 ca0, ca1, na0, na1;
  stageG(0, 0);
  loadA(0, ca0, ca1);
  __syncthreads();

#pragma unroll
  for (int g = 0; g < 8; ++g) {
    const int buf = g & 1;
    if (g < 7) {
      stageG(g + 1, buf ^ 1);
      loadA(g + 1, na0, na1);
    }
#pragma unroll
    for (int nt = 0; nt < 8; ++nt) {
      const bf16x8 b =
          *reinterpret_cast<const bf16x8*>(&Bl[buf][(nt * 64 + lane) * 8]);
      acc[0][nt] = __builtin_amdgcn_mfma_f32_16x16x32_bf16(ca0, b, acc[0][nt], 0, 0, 0);
      acc[1][nt] = __builtin_amdgcn_mfma_f32_16x16x32_bf16(ca1, b, acc[1][nt], 0, 0, 0);
    }
    __syncthreads();
    ca0 = na0;
    ca1 = na1;
  }

#pragma unroll
  for (int nt = 0; nt < 8; ++nt) {
    const int cidx = nt * 16 + lm;
    const float bv = bias[cidx];
#pragma unroll
    for (int mt = 0; mt < 2; ++mt) {
#pragma unroll
      for (int i = 0; i < 4; ++i) {
        const int r = rbase + mt * 16 + lk * 4 + i;
        if (r < N_NODES) {
          float v = acc[mt][nt][i] + bv;
          v = fmaxf(v, 0.0f);
          if (OUTF32) {
            Of[(size_t)r * DIM + cidx] = v;
          } else {
            Ohi[(size_t)r * DIM + cidx] = f32_to_bf16_rn(v);
          }
        }
      }
    }
  }
}

// ---------------- launcher ----------------
extern "C" void kernel_launch(void* const* d_in, const int* in_sizes, int n_in,
                              void* d_out, int out_size, void* d_ws,
                              size_t ws_size, hipStream_t stream) {
  const float* x = (const float*)d_in[0];
  const int* ei = (const int*)d_in[1];
  const float* Wl0 = (const float*)d_in[2];
  const float* bl0 = (const float*)d_in[3];
  const float* Wr0 = (const float*)d_in[4];
  const float* Wl1 = (const float*)d_in[5];
  const float* bl1 = (const float*)d_in[6];
  const float* Wr1 = (const float*)d_in[7];
  float* out = (float*)d_out;
  const int* src = ei;
  const int* dst = ei + N_EDGES;

  char* p = (char*)d_ws;
  auto alloc = [&](size_t bytes) {
    char* q = p;
    p += (bytes + 255) & ~(size_t)255;
    return q;
  };
  int* deg = (int*)alloc((size_t)N_NODES * 4);
  int* rowptr = (int*)alloc((size_t)(N_NODES + 1) * 4);
  int* head = (int*)alloc((size_t)N_NODES * 4);  // doubles as incl-scan temp
  int* col = (int*)alloc((size_t)N_EDGES * 4);
  int* bsum = (int*)alloc(128 * 4);
  int* boffs = (int*)alloc(128 * 4);
  unsigned short* Bp0 = (unsigned short*)alloc(32768 * 2);
  unsigned short* Bp1 = (unsigned short*)alloc(32768 * 2);
  unsigned short* xhi = (unsigned short*)alloc((size_t)N_NODES * DIM * 2);
  unsigned short* mhi = (unsigned short*)alloc((size_t)N_NODES * DIM * 2);
  unsigned short* h1hi = (unsigned short*)alloc((size_t)N_NODES * DIM * 2);

  const int nScanB = (N_NODES + 1023) / 1024;  // 98

  hipMemsetAsync(deg, 0, (size_t)N_NODES * 4, stream);
  prep_k<<<(65536 + N_NODES * DIM / 4 + 255) / 256, 256, 0, stream>>>(
      Wl0, Wr0, Wl1, Wr1, Bp0, Bp1, x, xhi);
  hist_k<<<(N_EDGES + 255) / 256, 256, 0, stream>>>(dst, deg);
  scan1_k<<<nScanB, 1024, 0, stream>>>(deg, head, bsum);
  scan2_k<<<1, 128, 0, stream>>>(bsum, boffs, nScanB);
  scan3_k<<<nScanB, 1024, 0, stream>>>(deg, head, boffs, rowptr, head);
  fill_k<<<(N_EDGES + 255) / 256, 256, 0, stream>>>(src, dst, head, col);

  const int nBlocks = (N_NODES + 127) / 128;  // 782
  const int aggBlocks = N_NODES / 16;         // 6250

  // layer 0: gather xhi -> mhi; gemm0 (A = mhi, H = xhi) -> h1hi
  agg_k<<<aggBlocks, 256, 0, stream>>>(xhi, rowptr, col, mhi);
  gemm_k<0><<<nBlocks, 256, 0, stream>>>(mhi, xhi, Bp0, bl0, h1hi, nullptr);
  // layer 1: gather h1hi -> mhi; gemm1 (A = mhi, H = h1hi) -> f32 out
  agg_k<<<aggBlocks, 256, 0, stream>>>(h1hi, rowptr, col, mhi);
  gemm_k<1><<<nBlocks, 256, 0, stream>>>(mhi, h1hi, Bp1, bl1, nullptr, out);
}

// Round 11
// 176.683 us; speedup vs baseline: 1.0612x; 1.0612x over previous
//
#include <hip/hip_runtime.h>

#define N_NODES 100000
#define N_EDGES 600000
#define DIM 128

typedef __attribute__((ext_vector_type(8))) short bf16x8;
typedef __attribute__((ext_vector_type(4))) float f32x4;

typedef __attribute__((address_space(1))) const unsigned int g_u32;
typedef __attribute__((address_space(3))) unsigned int l_u32;
__device__ __forceinline__ void stage16(const void* g, void* l) {
  __builtin_amdgcn_global_load_lds((g_u32*)g, (l_u32*)l, 16, 0, 0);
}

__device__ __forceinline__ unsigned short f32_to_bf16_rn(float f) {
  unsigned int u = __builtin_bit_cast(unsigned int, f);
  unsigned int r = (u + 0x7FFFu + ((u >> 16) & 1u)) >> 16;
  return (unsigned short)r;
}

// ---------------- prep: zero deg + pack weights (hi) + x -> bf16 hi ------
// Also zeroes deg[] (replaces hipMemsetAsync: runtime fillBuffer for 400 KB
// measured 40 µs in-graph — latency-bound tiny-grid fill).
// gid < 65536: weight packing (two layers x 32768).
// gid >= 65536: xsplit over 3.2M float4 -> bf16x4.
__global__ __launch_bounds__(256) void prep_k(
    const float* __restrict__ Wl0, const float* __restrict__ Wr0,
    const float* __restrict__ Wl1, const float* __restrict__ Wr1,
    unsigned short* __restrict__ P0, unsigned short* __restrict__ P1,
    const float* __restrict__ x, unsigned short* __restrict__ xhi,
    int* __restrict__ deg) {
  const int gid = blockIdx.x * 256 + threadIdx.x;
  if (gid < N_NODES) deg[gid] = 0;
  if (gid < 65536) {
    const int layer = gid >> 15;
    const int idx = gid & 32767;
    const int j = idx & 7;
    const int l = (idx >> 3) & 63;
    const int nt = (idx >> 9) & 7;
    const int g = idx >> 12;  // 0..7
    const int k = ((g & 3) << 5) + ((l >> 4) << 3) + j;
    const int n = (nt << 4) + (l & 15);
    const float* W = layer ? ((g < 4) ? Wl1 : Wr1) : ((g < 4) ? Wl0 : Wr0);
    (layer ? P1 : P0)[idx] = f32_to_bf16_rn(W[k * 128 + n]);
  } else {
    const int i = gid - 65536;  // one float4 per thread
    if (i < N_NODES * DIM / 4) {
      const float4 v = reinterpret_cast<const float4*>(x)[i];
      const float f[4] = {v.x, v.y, v.z, v.w};
      unsigned short h[4];
#pragma unroll
      for (int j = 0; j < 4; ++j) h[j] = f32_to_bf16_rn(f[j]);
      uint2 hp;
      hp.x = (unsigned)h[0] | ((unsigned)h[1] << 16);
      hp.y = (unsigned)h[2] | ((unsigned)h[3] << 16);
      reinterpret_cast<uint2*>(xhi)[i] = hp;
    }
  }
}

// ---------------- CSR build ----------------
__global__ void hist_k(const int* __restrict__ dst, int* __restrict__ deg) {
  int e = blockIdx.x * blockDim.x + threadIdx.x;
  if (e < N_EDGES) atomicAdd(&deg[dst[e]], 1);
}

__global__ __launch_bounds__(1024) void scan1_k(const int* __restrict__ deg,
                                                int* __restrict__ incl,
                                                int* __restrict__ bsum) {
  __shared__ int wsum[16];
  const int t = threadIdx.x, lane = t & 63, w = t >> 6;
  const int gi = blockIdx.x * 1024 + t;
  int v = (gi < N_NODES) ? deg[gi] : 0;
  int s = v;
#pragma unroll
  for (int off = 1; off < 64; off <<= 1) {
    int u = __shfl_up(s, off);
    if (lane >= off) s += u;
  }
  if (lane == 63) wsum[w] = s;
  __syncthreads();
  if (t < 16) {
    int ws = wsum[t];
#pragma unroll
    for (int off = 1; off < 16; off <<= 1) {
      int u = __shfl_up(ws, off);
      if (t >= off) ws += u;
    }
    wsum[t] = ws;
  }
  __syncthreads();
  const int val = s + (w ? wsum[w - 1] : 0);
  if (gi < N_NODES) incl[gi] = val;
  if (t == 1023) bsum[blockIdx.x] = val;
}

__global__ void scan2_k(const int* __restrict__ bsum, int* __restrict__ boffs,
                        int nb) {
  __shared__ int w0;
  const int t = threadIdx.x;  // 128 threads
  int v = (t < nb) ? bsum[t] : 0;
  int s = v;
#pragma unroll
  for (int off = 1; off < 64; off <<= 1) {
    int u = __shfl_up(s, off);
    if ((t & 63) >= off) s += u;
  }
  if (t == 63) w0 = s;
  __syncthreads();
  const int excl = s - v + ((t >> 6) ? w0 : 0);
  if (t < nb) boffs[t] = excl;
}

__global__ __launch_bounds__(1024) void scan3_k(const int* __restrict__ deg,
                                                const int* __restrict__ incl,
                                                const int* __restrict__ boffs,
                                                int* __restrict__ rowptr,
                                                int* __restrict__ head) {
  const int gi = blockIdx.x * 1024 + threadIdx.x;
  if (gi < N_NODES) {
    const int e = incl[gi] - deg[gi] + boffs[blockIdx.x];
    rowptr[gi] = e;
    head[gi] = e;
  }
  if (gi == 0) rowptr[N_NODES] = N_EDGES;
}

__global__ void fill_k(const int* __restrict__ src, const int* __restrict__ dst,
                       int* __restrict__ head, int* __restrict__ col) {
  int e = blockIdx.x * blockDim.x + threadIdx.x;
  if (e < N_EDGES) {
    int p = atomicAdd(&head[dst[e]], 1);
    col[p] = src[e];
  }
}

// ---------------- mean aggregation: gather bf16 hi-plane ----------------
// 16 nodes / 256-thread block; 16 lanes per node, 16 B (8 bf16) per lane.
// Depth-4 neighbor pipeline. Output: mean as bf16 hi plane.
__global__ __launch_bounds__(256) void agg_k(
    const unsigned short* __restrict__ plane, const int* __restrict__ rowptr,
    const int* __restrict__ col, unsigned short* __restrict__ mhi) {
  const int t = threadIdx.x;
  const int node = blockIdx.x * 16 + (t >> 4);
  const int q = t & 15;  // 16B granule within the 256B row
  const int beg = rowptr[node], end = rowptr[node + 1];
  const uint4* P = reinterpret_cast<const uint4*>(plane);
  float a[8] = {};

  auto accum = [&](uint4 v) {
    const unsigned int u[4] = {v.x, v.y, v.z, v.w};
#pragma unroll
    for (int w = 0; w < 4; ++w) {
      a[2 * w] += __builtin_bit_cast(float, u[w] << 16);
      a[2 * w + 1] += __builtin_bit_cast(float, u[w] & 0xFFFF0000u);
    }
  };

  for (int i = beg; i < end; i += 4) {
    const int i1 = min(i + 1, end - 1);
    const int i2 = min(i + 2, end - 1);
    const int i3 = min(i + 3, end - 1);
    const int c0 = col[i], c1 = col[i1], c2 = col[i2], c3 = col[i3];
    const uint4 v0 = P[(size_t)c0 * 16 + q];
    const uint4 v1 = P[(size_t)c1 * 16 + q];
    const uint4 v2 = P[(size_t)c2 * 16 + q];
    const uint4 v3 = P[(size_t)c3 * 16 + q];
    accum(v0);
    if (i + 1 < end) accum(v1);
    if (i + 2 < end) accum(v2);
    if (i + 3 < end) accum(v3);
  }

  const int d = end - beg;
  const float inv = 1.0f / (float)(d > 1 ? d : 1);
  unsigned int hw[4];
#pragma unroll
  for (int w = 0; w < 4; ++w) {
    const unsigned short h0 = f32_to_bf16_rn(a[2 * w] * inv);
    const unsigned short h1 = f32_to_bf16_rn(a[2 * w + 1] * inv);
    hw[w] = (unsigned)h0 | ((unsigned)h1 << 16);
  }
  uint4 ho = {hw[0], hw[1], hw[2], hw[3]};
  reinterpret_cast<uint4*>(mhi)[(size_t)node * 16 + q] = ho;
}

// ---------------- MFMA GEMM: out = relu(mean@Wl + b + h@Wr) ----------------
// Grid: 1563 blocks x 64 rows. Block: 256 thr / 4 waves; wave = 16 rows x
// N=128 (8 n-tiles). K loop: 8 g-tiles (g 0-3: Mhi x Wl; g 4-7: Hhi x Wr).
// B: 8 KB/g-tile, double-buffered LDS via global_load_lds, one barrier per
// g-tile. A fragment = direct bf16x8 load, register-prefetched one ahead.
template <int OUTF32>
__global__ __launch_bounds__(256, 4) void gemm_k(
    const unsigned short* __restrict__ Mhi, const unsigned short* __restrict__ Hhi,
    const unsigned short* __restrict__ Bp, const float* __restrict__ bias,
    unsigned short* __restrict__ Ohi, float* __restrict__ Of) {
  __shared__ unsigned short Bl[2][4096];  // 8 KB per buffer
  const int t = threadIdx.x;
  const int lane = t & 63;
  const int wid = t >> 6;
  const int rbase = blockIdx.x * 64 + wid * 16;
  const int lm = lane & 15, lk = lane >> 4;
  const size_t r0 = (size_t)min(rbase + lm, N_NODES - 1);

  f32x4 acc[8] = {};

  auto stageG = [&](int g, int nb) {
#pragma unroll
    for (int c = 0; c < 2; ++c) {
      const int e = (c * 256 + t) * 8;  // short index
      stage16(Bp + (size_t)g * 4096 + e, &Bl[nb][e]);
    }
  };
  auto loadA = [&](int g) {
    const unsigned short* P = (g < 4) ? Mhi : Hhi;
    const int ke = ((g & 3) << 5) + (lk << 3);
    return *reinterpret_cast<const bf16x8*>(P + r0 * DIM + ke);
  };

  stageG(0, 0);
  bf16x8 ca = loadA(0), na;
  __syncthreads();

#pragma unroll
  for (int g = 0; g < 8; ++g) {
    const int buf = g & 1;
    if (g < 7) {
      stageG(g + 1, buf ^ 1);
      na = loadA(g + 1);
    }
#pragma unroll
    for (int nt = 0; nt < 8; ++nt) {
      const bf16x8 b =
          *reinterpret_cast<const bf16x8*>(&Bl[buf][(nt * 64 + lane) * 8]);
      acc[nt] = __builtin_amdgcn_mfma_f32_16x16x32_bf16(ca, b, acc[nt], 0, 0, 0);
    }
    __syncthreads();
    ca = na;
  }

#pragma unroll
  for (int nt = 0; nt < 8; ++nt) {
    const int cidx = nt * 16 + lm;
    const float bv = bias[cidx];
#pragma unroll
    for (int i = 0; i < 4; ++i) {
      const int r = rbase + lk * 4 + i;
      if (r < N_NODES) {
        float v = acc[nt][i] + bv;
        v = fmaxf(v, 0.0f);
        if (OUTF32) {
          Of[(size_t)r * DIM + cidx] = v;
        } else {
          Ohi[(size_t)r * DIM + cidx] = f32_to_bf16_rn(v);
        }
      }
    }
  }
}

// ---------------- launcher ----------------
extern "C" void kernel_launch(void* const* d_in, const int* in_sizes, int n_in,
                              void* d_out, int out_size, void* d_ws,
                              size_t ws_size, hipStream_t stream) {
  const float* x = (const float*)d_in[0];
  const int* ei = (const int*)d_in[1];
  const float* Wl0 = (const float*)d_in[2];
  const float* bl0 = (const float*)d_in[3];
  const float* Wr0 = (const float*)d_in[4];
  const float* Wl1 = (const float*)d_in[5];
  const float* bl1 = (const float*)d_in[6];
  const float* Wr1 = (const float*)d_in[7];
  float* out = (float*)d_out;
  const int* src = ei;
  const int* dst = ei + N_EDGES;

  char* p = (char*)d_ws;
  auto alloc = [&](size_t bytes) {
    char* q = p;
    p += (bytes + 255) & ~(size_t)255;
    return q;
  };
  int* deg = (int*)alloc((size_t)N_NODES * 4);
  int* rowptr = (int*)alloc((size_t)(N_NODES + 1) * 4);
  int* head = (int*)alloc((size_t)N_NODES * 4);  // doubles as incl-scan temp
  int* col = (int*)alloc((size_t)N_EDGES * 4);
  int* bsum = (int*)alloc(128 * 4);
  int* boffs = (int*)alloc(128 * 4);
  unsigned short* Bp0 = (unsigned short*)alloc(32768 * 2);
  unsigned short* Bp1 = (unsigned short*)alloc(32768 * 2);
  unsigned short* xhi = (unsigned short*)alloc((size_t)N_NODES * DIM * 2);
  unsigned short* mhi = (unsigned short*)alloc((size_t)N_NODES * DIM * 2);
  unsigned short* h1hi = (unsigned short*)alloc((size_t)N_NODES * DIM * 2);

  const int nScanB = (N_NODES + 1023) / 1024;  // 98

  prep_k<<<(65536 + N_NODES * DIM / 4 + 255) / 256, 256, 0, stream>>>(
      Wl0, Wr0, Wl1, Wr1, Bp0, Bp1, x, xhi, deg);
  hist_k<<<(N_EDGES + 255) / 256, 256, 0, stream>>>(dst, deg);
  scan1_k<<<nScanB, 1024, 0, stream>>>(deg, head, bsum);
  scan2_k<<<1, 128, 0, stream>>>(bsum, boffs, nScanB);
  scan3_k<<<nScanB, 1024, 0, stream>>>(deg, head, boffs, rowptr, head);
  fill_k<<<(N_EDGES + 255) / 256, 256, 0, stream>>>(src, dst, head, col);

  const int nBlocks = (N_NODES + 63) / 64;    // 1563
  const int aggBlocks = N_NODES / 16;         // 6250

  // layer 0: gather xhi -> mhi; gemm0 (A = mhi, H = xhi) -> h1hi
  agg_k<<<aggBlocks, 256, 0, stream>>>(xhi, rowptr, col, mhi);
  gemm_k<0><<<nBlocks, 256, 0, stream>>>(mhi, xhi, Bp0, bl0, h1hi, nullptr);
  // layer 1: gather h1hi -> mhi; gemm1 (A = mhi, H = h1hi) -> f32 out
  agg_k<<<aggBlocks, 256, 0, stream>>>(h1hi, rowptr, col, mhi);
  gemm_k<1><<<nBlocks, 256, 0, stream>>>(mhi, h1hi, Bp1, bl1, nullptr, out);
}